// Round 1
// baseline (458.861 us; speedup 1.0000x reference)
//
#include <hip/hip_runtime.h>
#include <hip/hip_cooperative_groups.h>
#include <math.h>

#define BB 8
#define TT 4096
#define FF 1024
#define F4 (FF / 4)        // 256 float4 per row
#define TS 128             // t-chunks per batch
#define TCHUNK (TT / TS)   // 32 timesteps per chunk
#define NBLK (BB * TS)     // 1024 blocks, 4/CU on 256 CUs

namespace cg = cooperative_groups;

typedef float vfloat4 __attribute__((ext_vector_type(4)));

// ---------------------------------------------------------------------------
// Single cooperative kernel, three phases separated by grid.sync():
//  P1: masked column partial sums (valid-prefix rows only; fully-masked
//      chunks read nothing), part[b,ts,f].
//  P2: 256 blocks build k[b,f] = colsum/L and atomically reduce
//      Sk[b]=sum(k), Skk[b]=sum(k^2). No kc materialization:
//      num = dot(x,k) - mean(x)*Sk ; kd^2 = Skk - Sk^2/F.
//  P3: each block re-reads ITS OWN phase-1 chunk (L2/L3-hot), computes the
//      per-row gate, applies, nontemporal store. Padded rows: zero store only.
// ---------------------------------------------------------------------------
__global__ __launch_bounds__(256, 4) void fused_all(
    const float4* __restrict__ x4,
    const int*    __restrict__ mask,
    float4*       __restrict__ out4,
    float*        __restrict__ part,
    float*        __restrict__ kbuf,
    float*        __restrict__ Sk,
    float*        __restrict__ Skk)
{
    cg::grid_group grid = cg::this_grid();
    const int tid  = threadIdx.x;
    const int wave = tid >> 6;
    const int lane = tid & 63;
    const int blk  = blockIdx.x;
    const int b    = blk & 7;      // interleave b first: balances ragged tails
    const int ts   = blk >> 3;

    __shared__ float msh[TCHUNK];
    __shared__ float red[8][32];

    // ---- phase 0: zero the atomic scalars (ws is poisoned every iter) ----
    if (blk == 0 && tid < 2 * BB) {
        if (tid < BB) Sk[tid]       = 0.f;
        else          Skk[tid - BB] = 0.f;
    }

    // ---- phase 1: column partial sums over valid rows only ----
    if (tid < TCHUNK) msh[tid] = (float)mask[(size_t)b * TT + ts * TCHUNK + tid];
    __syncthreads();
    int nv = 0;                       // mask is a valid-prefix: rows [0,nv) valid
    #pragma unroll
    for (int i = 0; i < TCHUNK; ++i) nv += (msh[i] != 0.f) ? 1 : 0;

    if (nv > 0) {
        const float4* xb = x4 + ((size_t)b * TT + (size_t)ts * TCHUNK) * F4 + tid;
        float4 acc = make_float4(0.f, 0.f, 0.f, 0.f);
        #pragma unroll 8
        for (int t = 0; t < nv; ++t) {          // plain adds: prefix => m==1
            float4 v = xb[(size_t)t * F4];
            acc.x += v.x; acc.y += v.y; acc.z += v.z; acc.w += v.w;
        }
        ((float4*)part)[((size_t)b * TS + ts) * F4 + tid] = acc;
    }

    grid.sync();

    // ---- phase 2: k[b,f] + Sk/Skk, spread over 256 blocks ----
    if (blk < 256) {
        const int b2    = blk >> 5;
        const int fbase = (blk & 31) * 32;

        // valid length L (redundant per b-group; 16 KB L2-hot read)
        int c = 0;
        #pragma unroll
        for (int i = 0; i < 16; ++i) c += mask[(size_t)b2 * TT + tid + 256 * i];
        float fc = (float)c;
        #pragma unroll
        for (int off = 32; off; off >>= 1) fc += __shfl_xor(fc, off);
        if (lane == 0) red[0][wave] = fc;
        __syncthreads();
        const float Lf  = red[0][0] + red[0][1] + red[0][2] + red[0][3];
        const int   nts = ((int)Lf + TCHUNK - 1) / TCHUNK;  // only these chunks were written
        __syncthreads();

        const int f     = fbase + (tid & 31);
        const int slice = tid >> 5;            // 8 ts-slices per channel
        float s = 0.f;
        for (int t = slice; t < nts; t += 8)
            s += part[((size_t)b2 * TS + t) * FF + f];
        red[slice][tid & 31] = s;
        __syncthreads();
        if (tid < 32) {
            float sum = 0.f;
            #pragma unroll
            for (int sl = 0; sl < 8; ++sl) sum += red[sl][tid];
            const float kv = sum / Lf;
            kbuf[(size_t)b2 * FF + fbase + tid] = kv;
            float a = kv, q = kv * kv;
            #pragma unroll
            for (int off = 16; off; off >>= 1) {   // reduce lanes 0..31
                a += __shfl_xor(a, off);
                q += __shfl_xor(q, off);
            }
            if (tid == 0) {
                atomicAdd(&Sk[b2],  a);
                atomicAdd(&Skk[b2], q);
            }
        }
    }

    grid.sync();

    // ---- phase 3: gate + apply on this block's own chunk ----
    const float sk  = Sk[b];
    const float skk = Skk[b];
    const float kd  = sqrtf(fmaxf(skk - sk * sk * (1.0f / FF), 0.f));

    const float4* kb4 = (const float4*)(kbuf + (size_t)b * FF);
    float4 kv[4];                                  // k row hoisted to registers
    #pragma unroll
    for (int j = 0; j < 4; ++j) kv[j] = kb4[lane + 64 * j];

    const size_t chunkbase = ((size_t)b * TT + (size_t)ts * TCHUNK) * F4;
    for (int i = 7; i >= 0; --i) {                 // LIFO: hottest rows first
        const int r = wave * 8 + i;
        const size_t row = chunkbase + (size_t)r * F4;
        vfloat4* orow = (vfloat4*)(out4 + row);
        if (msh[r] == 0.f) {                       // padded row: zero, no reads
            vfloat4 z = (vfloat4)(0.f);
            #pragma unroll
            for (int j = 0; j < 4; ++j)
                __builtin_nontemporal_store(z, orow + lane + 64 * j);
            continue;
        }
        const float4* xrow = x4 + row;
        float4 xv[4];
        #pragma unroll
        for (int j = 0; j < 4; ++j) xv[j] = xrow[lane + 64 * j];

        float s1 = 0.f, s2 = 0.f, s3 = 0.f;
        #pragma unroll
        for (int j = 0; j < 4; ++j) {
            s1 += xv[j].x + xv[j].y + xv[j].z + xv[j].w;
            s2 = fmaf(xv[j].x, xv[j].x, fmaf(xv[j].y, xv[j].y,
                 fmaf(xv[j].z, xv[j].z, fmaf(xv[j].w, xv[j].w, s2))));
            s3 = fmaf(xv[j].x, kv[j].x, fmaf(xv[j].y, kv[j].y,
                 fmaf(xv[j].z, kv[j].z, fmaf(xv[j].w, kv[j].w, s3))));
        }
        #pragma unroll
        for (int off = 32; off; off >>= 1) {
            s1 += __shfl_xor(s1, off);
            s2 += __shfl_xor(s2, off);
            s3 += __shfl_xor(s3, off);
        }
        const float mx  = s1 * (1.0f / FF);
        const float num = s3 - mx * sk;                        // dot(x_c, k_c)
        const float qd  = sqrtf(fmaxf(s2 - s1 * s1 * (1.0f / FF), 0.f));
        const float C   = num / (qd * kd);
        const float A   = 1.0f / (1.0f + __expf(C));           // 1 - sigmoid
        #pragma unroll
        for (int j = 0; j < 4; ++j) {
            vfloat4 o;
            o.x = xv[j].x * A; o.y = xv[j].y * A;
            o.z = xv[j].z * A; o.w = xv[j].w * A;
            __builtin_nontemporal_store(o, orow + lane + 64 * j);
        }
    }
}

// ---------------------------------------------------------------------------
extern "C" void kernel_launch(void* const* d_in, const int* in_sizes, int n_in,
                              void* d_out, int out_size, void* d_ws, size_t ws_size,
                              hipStream_t stream) {
    const float4* x4   = (const float4*)d_in[0];
    const int*    mask = (const int*)d_in[1];
    float4*       out4 = (float4*)d_out;

    // workspace (floats): part[B*TS*F] | k[B*F] | Sk[B] | Skk[B]
    float* part = (float*)d_ws;
    float* kbuf = part + (size_t)BB * TS * FF;
    float* Sk   = kbuf + (size_t)BB * FF;
    float* Skk  = Sk + BB;

    void* args[] = { (void*)&x4, (void*)&mask, (void*)&out4,
                     (void*)&part, (void*)&kbuf, (void*)&Sk, (void*)&Skk };
    hipLaunchCooperativeKernel((const void*)fused_all, dim3(NBLK), dim3(256),
                               args, 0, stream);
}

// Round 2
// 249.918 us; speedup vs baseline: 1.8360x; 1.8360x over previous
//
#include <hip/hip_runtime.h>
#include <math.h>

#define BB 8
#define TT 4096
#define FF 1024
#define F4 (FF / 4)        // 256 float4 per row
#define TS 128             // t-chunks per batch
#define TCHUNK (TT / TS)   // 32 timesteps per chunk

typedef float vfloat4 __attribute__((ext_vector_type(4)));

// ---------------------------------------------------------------------------
// Kernel 1: partial masked column sums with valid-prefix skip.
// mask is a prefix (t < length), so rows [0, nv) of each chunk are valid and
// the rest are never read. Fully-dead chunks read/write nothing (k2 bounds
// its reduction by nts = ceil(L/TCHUNK)). ts==0 blocks zero Sk/Skk for k2's
// atomics. grid: (TS, BB), block: 256 (each thread owns 4 consecutive f's).
// ---------------------------------------------------------------------------
__global__ __launch_bounds__(256) void k1_partial(const float4* __restrict__ x4,
                                                  const int* __restrict__ mask,
                                                  float4* __restrict__ part4,
                                                  float* __restrict__ Sk,
                                                  float* __restrict__ Skk) {
    const int ts  = blockIdx.x;
    const int b   = blockIdx.y;
    const int tid = threadIdx.x;

    if (ts == 0 && tid == 0) { Sk[b] = 0.f; Skk[b] = 0.f; }   // ws is poisoned

    __shared__ int msh[TCHUNK];
    if (tid < TCHUNK) msh[tid] = mask[(size_t)b * TT + ts * TCHUNK + tid];
    __syncthreads();
    int nv = 0;                              // prefix mask => count == boundary
    #pragma unroll
    for (int i = 0; i < TCHUNK; ++i) nv += msh[i];
    if (nv == 0) return;                     // dead chunk: no reads, no store

    const float4* xb = x4 + ((size_t)b * TT + (size_t)ts * TCHUNK) * F4 + tid;
    float4 acc = make_float4(0.f, 0.f, 0.f, 0.f);
    #pragma unroll 8
    for (int t = 0; t < nv; ++t) {           // prefix => plain adds, no mask mul
        float4 v = xb[(size_t)t * F4];
        acc.x += v.x; acc.y += v.y; acc.z += v.z; acc.w += v.w;
    }
    part4[((size_t)b * TS + ts) * F4 + tid] = acc;
}

// ---------------------------------------------------------------------------
// Kernel 2: k[b,f] = colsum/L, plus Sk[b]=sum(k), Skk[b]=sum(k^2) via atomics.
// 256 blocks (32 per batch x 32-channel groups) instead of the old 8 — kills
// the whole-device serialization bubble. Reads only the nts written chunks.
// grid: 256, block: 256.
// ---------------------------------------------------------------------------
__global__ __launch_bounds__(256) void k2_stats(const float* __restrict__ part,
                                                const int* __restrict__ mask,
                                                float* __restrict__ kbuf,
                                                float* __restrict__ Sk,
                                                float* __restrict__ Skk) {
    __shared__ float red[8][32];
    __shared__ float Lred[4];

    const int tid   = threadIdx.x;
    const int wave  = tid >> 6;
    const int lane  = tid & 63;
    const int b2    = blockIdx.x >> 5;
    const int fbase = (blockIdx.x & 31) * 32;

    // ---- valid length L (mask is L2/L3-hot after k1) ----
    int c = 0;
    #pragma unroll
    for (int i = 0; i < 16; ++i) c += mask[(size_t)b2 * TT + tid + 256 * i];
    float fc = (float)c;
    #pragma unroll
    for (int off = 32; off; off >>= 1) fc += __shfl_xor(fc, off);
    if (lane == 0) Lred[wave] = fc;
    __syncthreads();
    const float Lf  = Lred[0] + Lred[1] + Lred[2] + Lred[3];
    const int   nts = ((int)Lf + TCHUNK - 1) / TCHUNK;   // only these were written

    // ---- column sums: 8 ts-slices per channel ----
    const int f     = fbase + (tid & 31);
    const int slice = tid >> 5;
    float s = 0.f;
    for (int t = slice; t < nts; t += 8)
        s += part[((size_t)b2 * TS + t) * FF + f];
    red[slice][tid & 31] = s;
    __syncthreads();

    if (tid < 32) {
        float sum = 0.f;
        #pragma unroll
        for (int sl = 0; sl < 8; ++sl) sum += red[sl][tid];
        const float kv = sum / Lf;
        kbuf[(size_t)b2 * FF + fbase + tid] = kv;
        float a = kv, q = kv * kv;
        #pragma unroll
        for (int off = 16; off; off >>= 1) {             // lanes 0..31 reduce
            a += __shfl_xor(a, off);
            q += __shfl_xor(q, off);
        }
        if (tid == 0) {
            atomicAdd(&Sk[b2],  a);
            atomicAdd(&Skk[b2], q);
        }
    }
}

// ---------------------------------------------------------------------------
// Kernel 3: wave-per-row gate + apply (round-0 fast structure). 64 lanes cover
// one 1024-f row, pure shuffle reduction, nontemporal stores. Consumes raw
// kbuf + Sk/Skk:  num = dot(x,k) - mean(x)*Sk ;  kd^2 = Skk - Sk^2/F.
// x reads are L3-hot from k1. grid: (TT/4, BB), block: 256.
// ---------------------------------------------------------------------------
__global__ __launch_bounds__(256) void k3_apply(const float4* __restrict__ x4,
                                                const int* __restrict__ mask,
                                                const float4* __restrict__ kb4,
                                                const float* __restrict__ Sk,
                                                const float* __restrict__ Skk,
                                                float4* __restrict__ out4) {
    const int wave = threadIdx.x >> 6;
    const int lane = threadIdx.x & 63;
    const int t    = blockIdx.x * 4 + wave;
    const int b    = blockIdx.y;
    const size_t row = ((size_t)b * TT + t) * F4;

    vfloat4* orow = (vfloat4*)(out4 + row);
    if (mask[(size_t)b * TT + t] == 0) {          // padded row: zero, no reads
        vfloat4 z = (vfloat4)(0.f);
        #pragma unroll
        for (int j = 0; j < 4; ++j)
            __builtin_nontemporal_store(z, orow + lane + 64 * j);
        return;
    }

    const float4* xrow = x4 + row;
    const float4* krow = kb4 + (size_t)b * F4;
    float4 xv[4], kv[4];
    #pragma unroll
    for (int j = 0; j < 4; ++j) {
        xv[j] = xrow[lane + 64 * j];              // 1 KB coalesced per load
        kv[j] = krow[lane + 64 * j];              // L2-hot (4 KB per batch)
    }

    float s1 = 0.f, s2 = 0.f, s3 = 0.f;
    #pragma unroll
    for (int j = 0; j < 4; ++j) {
        s1 += xv[j].x + xv[j].y + xv[j].z + xv[j].w;
        s2 = fmaf(xv[j].x, xv[j].x, fmaf(xv[j].y, xv[j].y,
             fmaf(xv[j].z, xv[j].z, fmaf(xv[j].w, xv[j].w, s2))));
        s3 = fmaf(xv[j].x, kv[j].x, fmaf(xv[j].y, kv[j].y,
             fmaf(xv[j].z, kv[j].z, fmaf(xv[j].w, kv[j].w, s3))));
    }
    #pragma unroll
    for (int off = 32; off; off >>= 1) {
        s1 += __shfl_xor(s1, off);
        s2 += __shfl_xor(s2, off);
        s3 += __shfl_xor(s3, off);
    }

    const float sk  = Sk[b];
    const float kd  = sqrtf(fmaxf(Skk[b] - sk * sk * (1.0f / FF), 0.f));
    const float mx  = s1 * (1.0f / FF);
    const float num = s3 - mx * sk;                       // dot(x_c, k_c)
    const float qd  = sqrtf(fmaxf(s2 - s1 * s1 * (1.0f / FF), 0.f));
    const float C   = num / (qd * kd);
    const float A   = 1.0f / (1.0f + __expf(C));          // 1 - sigmoid(C)

    #pragma unroll
    for (int j = 0; j < 4; ++j) {
        vfloat4 o;
        o.x = xv[j].x * A; o.y = xv[j].y * A;
        o.z = xv[j].z * A; o.w = xv[j].w * A;
        __builtin_nontemporal_store(o, orow + lane + 64 * j);
    }
}

// ---------------------------------------------------------------------------
extern "C" void kernel_launch(void* const* d_in, const int* in_sizes, int n_in,
                              void* d_out, int out_size, void* d_ws, size_t ws_size,
                              hipStream_t stream) {
    const float* x    = (const float*)d_in[0];
    const int*   mask = (const int*)d_in[1];
    float*       out  = (float*)d_out;

    // workspace (floats): part[B*TS*F] | kbuf[B*F] | Sk[B] | Skk[B]
    float* part = (float*)d_ws;
    float* kbuf = part + (size_t)BB * TS * FF;
    float* Sk   = kbuf + (size_t)BB * FF;
    float* Skk  = Sk + BB;

    k1_partial<<<dim3(TS, BB), 256, 0, stream>>>((const float4*)x, mask,
                                                 (float4*)part, Sk, Skk);
    k2_stats<<<256, 256, 0, stream>>>(part, mask, kbuf, Sk, Skk);
    k3_apply<<<dim3(TT / 4, BB), 256, 0, stream>>>((const float4*)x, mask,
                                                   (const float4*)kbuf, Sk, Skk,
                                                   (float4*)out);
}